// Round 3
// baseline (99.289 us; speedup 1.0000x reference)
//
#include <hip/hip_runtime.h>
#include <math.h>

// MAM dense: C[i,j] = max_k(A[i,k]*W[j,k]) + min_k(A[i,k]*W[j,k]) + bias[j]
// A = x flat [M=2048, K=768]; W [N=768, K=768] row-major; out [M,N] f32.
// VALU-bound kernel. This round: inline-asm v_max3/v_min3 (forced fusion),
// v_pk_mul_f32 via <2 x float>, TM=8 x TN=3 register tile, 1 block/CU with
// big VGPR budget + register-prefetch staging.

#define M_DIM 2048
#define N_DIM 768
#define K_DIM 768

#define BM 128
#define BN 48
#define BK 64
#define TM 8
#define TN 3
#define NT_TILES (K_DIM / BK)   // 12
#define KP (BK / 2)             // 32 k-pair rows per tile

// LDS dword strides. SA multiple of 4 keeps A b128 reads 16B-aligned.
#define SA (2 * BM + 4)   // 260
#define SB (2 * BN + 2)   // 98

typedef __attribute__((ext_vector_type(2))) float f32x2;
typedef __attribute__((ext_vector_type(4))) float f32x4;

__device__ __forceinline__ float max3f(float a, float b, float c) {
    float d;
    asm("v_max3_f32 %0, %1, %2, %3" : "=v"(d) : "v"(a), "v"(b), "v"(c));
    return d;
}
__device__ __forceinline__ float min3f(float a, float b, float c) {
    float d;
    asm("v_min3_f32 %0, %1, %2, %3" : "=v"(d) : "v"(a), "v"(b), "v"(c));
    return d;
}

__global__ __launch_bounds__(256, 1) void mam_kernel(
    const float* __restrict__ A, const float* __restrict__ W,
    const float* __restrict__ bias, float* __restrict__ out)
{
    __shared__ __align__(16) float As[KP * SA];  // As[kk2*SA + 2*m] = pair {A[2kk2][m], A[2kk2+1][m]}
    __shared__ __align__(16) float Bs[KP * SB];  // Bs[kk2*SB + 2*n] = pair for W col n

    const int tid = threadIdx.x;
    const int m0 = blockIdx.y * BM;
    const int n0 = blockIdx.x * BN;
    const int mt = tid >> 4;   // 0..15  -> rows  mt*8 .. mt*8+7
    const int nt = tid & 15;   // 0..15  -> cols  nt*3 .. nt*3+2

    float amax[TM][TN], amin[TM][TN];
#pragma unroll
    for (int i = 0; i < TM; ++i)
#pragma unroll
        for (int j = 0; j < TN; ++j) {
            amax[i][j] = -INFINITY;
            amin[i][j] =  INFINITY;
        }

    // A staging: thread -> row ar (0..127), k-half ak (0 or 32); 8 float4 loads.
    const int ar = tid >> 1;
    const int ak = (tid & 1) * 32;
    const int akk2 = (tid & 1) * 16;   // base k-pair row
    const float* Aq = A + (size_t)(m0 + ar) * K_DIM + ak;

    // B staging: flat float4 chunk c = tid + 256*j -> row c>>4 (0..47), k-ofs (c&15)*4.
    const float* Wq = W + (size_t)n0 * K_DIM;

    float4 pa[8], pb[3];

    // prefetch tile 0
#pragma unroll
    for (int q = 0; q < 8; ++q)
        pa[q] = *(const float4*)(Aq + 4 * q);
#pragma unroll
    for (int j = 0; j < 3; ++j) {
        const int c = tid + 256 * j;
        pb[j] = *(const float4*)(Wq + (size_t)(c >> 4) * K_DIM + (c & 15) * 4);
    }

    for (int kt = 0; kt < NT_TILES; ++kt) {
        // ---- write prefetched registers to LDS (k-pair interleaved) ----
#pragma unroll
        for (int q = 0; q < 8; ++q) {
            const int kk2 = akk2 + 2 * q;
            *(float2*)&As[(kk2 + 0) * SA + 2 * ar] = make_float2(pa[q].x, pa[q].y);
            *(float2*)&As[(kk2 + 1) * SA + 2 * ar] = make_float2(pa[q].z, pa[q].w);
        }
#pragma unroll
        for (int j = 0; j < 3; ++j) {
            const int c   = tid + 256 * j;
            const int rb  = c >> 4;
            const int kk2 = (c & 15) * 2;
            *(float2*)&Bs[(kk2 + 0) * SB + 2 * rb] = make_float2(pb[j].x, pb[j].y);
            *(float2*)&Bs[(kk2 + 1) * SB + 2 * rb] = make_float2(pb[j].z, pb[j].w);
        }
        __syncthreads();

        // ---- issue next tile's global loads (latency hides under compute) ----
        if (kt + 1 < NT_TILES) {
            const float* An = Aq + (kt + 1) * BK;
#pragma unroll
            for (int q = 0; q < 8; ++q)
                pa[q] = *(const float4*)(An + 4 * q);
            const float* Wn = Wq + (kt + 1) * BK;
#pragma unroll
            for (int j = 0; j < 3; ++j) {
                const int c = tid + 256 * j;
                pb[j] = *(const float4*)(Wn + (size_t)(c >> 4) * K_DIM + (c & 15) * 4);
            }
        }

        // ---- compute over 32 k-pair rows ----
#pragma unroll 8
        for (int kk2 = 0; kk2 < KP; ++kk2) {
            const float* Ab = &As[kk2 * SA + mt * (2 * TM)];
            const f32x4 a01 = *(const f32x4*)(Ab + 0);
            const f32x4 a23 = *(const f32x4*)(Ab + 4);
            const f32x4 a45 = *(const f32x4*)(Ab + 8);
            const f32x4 a67 = *(const f32x4*)(Ab + 12);
            const f32x2 av[TM] = {a01.xy, a01.zw, a23.xy, a23.zw,
                                  a45.xy, a45.zw, a67.xy, a67.zw};
            const float* Bb = &Bs[kk2 * SB + nt * (2 * TN)];
            const f32x2 bv[TN] = { *(const f32x2*)(Bb + 0),
                                   *(const f32x2*)(Bb + 2),
                                   *(const f32x2*)(Bb + 4) };
#pragma unroll
            for (int i = 0; i < TM; ++i)
#pragma unroll
                for (int j = 0; j < TN; ++j) {
                    const f32x2 p = av[i] * bv[j];   // v_pk_mul_f32
                    amax[i][j] = max3f(amax[i][j], p.x, p.y);
                    amin[i][j] = min3f(amin[i][j], p.x, p.y);
                }
        }
        __syncthreads();   // all waves done reading before next overwrite
    }

    // ---- epilogue ----
    const float b0 = bias[n0 + nt * TN + 0];
    const float b1 = bias[n0 + nt * TN + 1];
    const float b2 = bias[n0 + nt * TN + 2];
#pragma unroll
    for (int i = 0; i < TM; ++i) {
        float* o = &out[(size_t)(m0 + mt * TM + i) * N_DIM + n0 + nt * TN];
        o[0] = amax[i][0] + amin[i][0] + b0;
        o[1] = amax[i][1] + amin[i][1] + b1;
        o[2] = amax[i][2] + amin[i][2] + b2;
    }
}

extern "C" void kernel_launch(void* const* d_in, const int* in_sizes, int n_in,
                              void* d_out, int out_size, void* d_ws, size_t ws_size,
                              hipStream_t stream) {
    const float* x    = (const float*)d_in[0];   // [2,1024,768] -> [2048,768]
    const float* w    = (const float*)d_in[1];   // [768,768] row-major [N][K]
    const float* bias = (const float*)d_in[2];   // [768]
    float* out = (float*)d_out;                  // [2048,768]

    dim3 grid(N_DIM / BN, M_DIM / BM);           // (16, 16) = 256 blocks = 1/CU
    mam_kernel<<<grid, 256, 0, stream>>>(x, w, bias, out);
}

// Round 4
// 74.805 us; speedup vs baseline: 1.3273x; 1.3273x over previous
//
#include <hip/hip_runtime.h>
#include <math.h>

// MAM dense: C[i,j] = max_k(A[i,k]*W[j,k]) + min_k(A[i,k]*W[j,k]) + bias[j]
// A = x flat [M=2048, K=768]; W [N=768, K=768] row-major; out [M,N] f32.
// VALU-bound. This round: R1's proven occupancy (768 blocks = 3/CU = 3 waves/SIMD)
// + R3's forced v_max3/v_min3 asm + BK=64 + constant-offset LDS reads (no per-iter
// address math; bases are loop-invariant across all k-tiles).

#define M_DIM 2048
#define N_DIM 768
#define K_DIM 768

#define BM 64
#define BN 32
#define BK 64
#define KP (BK / 2)            // 32 k-pair rows per tile
#define NTILES (K_DIM / BK)    // 12

// LDS dword strides; multiples of 4 keep b128 accesses 16B-aligned.
#define SA (2 * BM + 4)   // 132
#define SB (2 * BN + 4)   // 68

typedef __attribute__((ext_vector_type(4))) float f32x4;

__device__ __forceinline__ float max3f(float a, float b, float c) {
    float d;
    asm("v_max3_f32 %0, %1, %2, %3" : "=v"(d) : "v"(a), "v"(b), "v"(c));
    return d;
}
__device__ __forceinline__ float min3f(float a, float b, float c) {
    float d;
    asm("v_min3_f32 %0, %1, %2, %3" : "=v"(d) : "v"(a), "v"(b), "v"(c));
    return d;
}

__global__ __launch_bounds__(256, 3) void mam_kernel(
    const float* __restrict__ A, const float* __restrict__ W,
    const float* __restrict__ bias, float* __restrict__ out)
{
    // k-pair-interleaved tiles: As[kk2*SA + 2*m] = {A[2kk2][m], A[2kk2+1][m]}
    __shared__ __align__(16) float As[KP * SA];   // 16896 B
    __shared__ __align__(16) float Bs[KP * SB];   //  8704 B  (25.6 KB total, 3 blocks/CU ok)

    const int tid = threadIdx.x;
    const int m0 = blockIdx.y * BM;
    const int n0 = blockIdx.x * BN;
    const int mt = tid >> 4;   // 0..15 -> rows mt*4..mt*4+3
    const int nt = tid & 15;   // 0..15 -> cols nt*2..nt*2+1

    float amax[4][2], amin[4][2];
#pragma unroll
    for (int i = 0; i < 4; ++i)
#pragma unroll
        for (int j = 0; j < 2; ++j) {
            amax[i][j] = -INFINITY;
            amin[i][j] =  INFINITY;
        }

    // A staging: thread -> row ar (0..63), 16 consecutive k at offset (tid&3)*16
    const int ar  = tid >> 2;
    const int aks = tid & 3;
    // B staging: thread -> row br (0..31), 8 consecutive k at offset (tid&7)*8
    const int br  = tid >> 3;
    const int bks = tid & 7;

    const float* Ap = A + (size_t)(m0 + ar) * K_DIM + aks * 16;
    const float* Wp = W + (size_t)(n0 + br) * K_DIM + bks * 8;

    // hoist bias loads (latency hidden under main loop)
    const float bb0 = bias[n0 + nt * 2 + 0];
    const float bb1 = bias[n0 + nt * 2 + 1];

    // loop-invariant LDS addresses
    float* aw = &As[(aks * 8) * SA + 2 * ar];        // staging write base (A)
    float* bw = &Bs[(bks * 4) * SB + 2 * br];        // staging write base (B)
    const float* Ard = &As[(mt * 4) * 2];            // compute read base (A)
    const float* Brd = &Bs[(nt * 2) * 2];            // compute read base (B)

    float4 pa[4], pb[2];
    // prefetch tile 0 into registers
#pragma unroll
    for (int q = 0; q < 4; ++q) pa[q] = *(const float4*)(Ap + 4 * q);
#pragma unroll
    for (int q = 0; q < 2; ++q) pb[q] = *(const float4*)(Wp + 4 * q);

    for (int kt = 0; kt < NTILES; ++kt) {
        if (kt) __syncthreads();   // previous tile's reads complete before overwrite

        // write prefetched registers to LDS, k-pair interleaved (b64 stores)
#pragma unroll
        for (int q = 0; q < 4; ++q) {
            *(float2*)(aw + (2 * q + 0) * SA) = make_float2(pa[q].x, pa[q].y);
            *(float2*)(aw + (2 * q + 1) * SA) = make_float2(pa[q].z, pa[q].w);
        }
#pragma unroll
        for (int q = 0; q < 2; ++q) {
            *(float2*)(bw + (2 * q + 0) * SB) = make_float2(pb[q].x, pb[q].y);
            *(float2*)(bw + (2 * q + 1) * SB) = make_float2(pb[q].z, pb[q].w);
        }
        __syncthreads();

        // issue next tile's global loads; latency hides under 32-iter compute
        if (kt + 1 < NTILES) {
            const float* An = Ap + (kt + 1) * BK;
            const float* Wn = Wp + (kt + 1) * BK;
#pragma unroll
            for (int q = 0; q < 4; ++q) pa[q] = *(const float4*)(An + 4 * q);
#pragma unroll
            for (int q = 0; q < 2; ++q) pb[q] = *(const float4*)(Wn + 4 * q);
        }

        // compute: 32 k-pair rows, fully unrolled, constant LDS offsets
#pragma unroll
        for (int kk2 = 0; kk2 < KP; ++kk2) {
            const f32x4 a01 = *(const f32x4*)(Ard + kk2 * SA);
            const f32x4 a23 = *(const f32x4*)(Ard + kk2 * SA + 4);
            const f32x4 b01 = *(const f32x4*)(Brd + kk2 * SB);
            const float am[4][2] = {{a01.x, a01.y}, {a01.z, a01.w},
                                    {a23.x, a23.y}, {a23.z, a23.w}};
            const float bn_[2][2] = {{b01.x, b01.y}, {b01.z, b01.w}};
#pragma unroll
            for (int i = 0; i < 4; ++i)
#pragma unroll
                for (int j = 0; j < 2; ++j) {
                    const float p0 = am[i][0] * bn_[j][0];
                    const float p1 = am[i][1] * bn_[j][1];
                    amax[i][j] = max3f(amax[i][j], p0, p1);
                    amin[i][j] = min3f(amin[i][j], p0, p1);
                }
        }
    }

    // epilogue
#pragma unroll
    for (int i = 0; i < 4; ++i) {
        float2 o;
        o.x = amax[i][0] + amin[i][0] + bb0;
        o.y = amax[i][1] + amin[i][1] + bb1;
        *(float2*)&out[(size_t)(m0 + mt * 4 + i) * N_DIM + n0 + nt * 2] = o;
    }
}

extern "C" void kernel_launch(void* const* d_in, const int* in_sizes, int n_in,
                              void* d_out, int out_size, void* d_ws, size_t ws_size,
                              hipStream_t stream) {
    const float* x    = (const float*)d_in[0];   // [2,1024,768] -> [2048,768]
    const float* w    = (const float*)d_in[1];   // [768,768] row-major [N][K]
    const float* bias = (const float*)d_in[2];   // [768]
    float* out = (float*)d_out;                  // [2048,768]

    dim3 grid(N_DIM / BN, M_DIM / BM);           // (24, 32) = 768 blocks = 3/CU
    mam_kernel<<<grid, 256, 0, stream>>>(x, w, bias, out);
}

// Round 6
// 68.854 us; speedup vs baseline: 1.4420x; 1.0864x over previous
//
#include <hip/hip_runtime.h>
#include <math.h>

// MAM dense: C[i,j] = max_k(A[i,k]*W[j,k]) + min_k(A[i,k]*W[j,k]) + bias[j]
// A = x flat [M=2048, K=768]; W [N=768, K=768] row-major; out [M,N] f32.
// Packed-fp16 inner loop (v_pk_mul_f16 + v_pk_max_f16 + v_pk_min_f16 = 3 VALU
// per 2 products), even-k/odd-k extrema combined in epilogue. LDS strides give
// 2-way (free) staging writes and broadcast/conflict-free reads.
// Precision: |p|<=0.19, fp16 err <=~8e-4 abs vs 2.56e-3 threshold.

#define M_DIM 2048
#define N_DIM 768
#define K_DIM 768

#define BM 64
#define BN 32
#define BK 64
#define KP (BK / 2)            // 32 k-pair rows per tile
#define NTILES (K_DIM / BK)    // 12

// LDS strides in h16x2 (4B) units.
#define SAH 66
#define SBH 34

typedef _Float16 h2 __attribute__((ext_vector_type(2)));   // 4 B
typedef _Float16 h4 __attribute__((ext_vector_type(4)));   // 8 B (b64)

__device__ __forceinline__ h2 cvt_pk(float x, float y) {
    return __builtin_bit_cast(h2, __builtin_amdgcn_cvt_pkrtz(x, y));
}

__global__ __launch_bounds__(256, 3) void mam_kernel(
    const float* __restrict__ A, const float* __restrict__ W,
    const float* __restrict__ bias, float* __restrict__ out)
{
    __shared__ __align__(16) h2 As[KP * SAH];   // As[kk2*SAH + m] = {A[2kk2][m], A[2kk2+1][m]} fp16
    __shared__ __align__(16) h2 Bs[KP * SBH];   // Bs[kk2*SBH + n] = pair for W col n

    const int tid = threadIdx.x;
    const int m0 = blockIdx.y * BM;
    const int n0 = blockIdx.x * BN;
    const int mt = tid >> 4;   // 0..15 -> rows mt*4..mt*4+3
    const int nt = tid & 15;   // 0..15 -> cols nt*2..nt*2+1

    // running even-k / odd-k extrema, packed
    h2 pmax[4][2], pmin[4][2];
    const _Float16 HMIN = (_Float16)(-65504.0f), HMAX = (_Float16)(65504.0f);
#pragma unroll
    for (int i = 0; i < 4; ++i)
#pragma unroll
        for (int j = 0; j < 2; ++j) {
            pmax[i][j] = (h2){HMIN, HMIN};
            pmin[i][j] = (h2){HMAX, HMAX};
        }

    // ---- staging maps (flat float4 chunks, perfectly coalesced) ----
    const int arow = tid >> 4;          // base row comp (row = arow + 16q)
    const int akc  = tid & 15;          // k-chunk -> k = akc*4, kk2 = 2*akc
    const float* Ap = A + (size_t)m0 * K_DIM + akc * 4;
    const float* Wp = W + (size_t)n0 * K_DIM + akc * 4;

    const float bb0 = bias[n0 + nt * 2 + 0];
    const float bb1 = bias[n0 + nt * 2 + 1];

    // loop-invariant LDS bases
    h2* awr = &As[2 * akc * SAH];            // + row in [0,64)
    h2* bwr = &Bs[2 * akc * SBH];
    const h2* Ard = &As[mt * 4];
    const h2* Brd = &Bs[nt * 2];

    float4 pa[4], pb[2];
#pragma unroll
    for (int q = 0; q < 4; ++q)
        pa[q] = *(const float4*)(Ap + (size_t)(arow + 16 * q) * K_DIM);
#pragma unroll
    for (int q = 0; q < 2; ++q)
        pb[q] = *(const float4*)(Wp + (size_t)(arow + 16 * q) * K_DIM);

    for (int kt = 0; kt < NTILES; ++kt) {
        if (kt) __syncthreads();

        // convert f32->fp16 (v_cvt_pkrtz) and write, 2-way banked (free)
#pragma unroll
        for (int q = 0; q < 4; ++q) {
            awr[0 * SAH + arow + 16 * q] = cvt_pk(pa[q].x, pa[q].y);
            awr[1 * SAH + arow + 16 * q] = cvt_pk(pa[q].z, pa[q].w);
        }
#pragma unroll
        for (int q = 0; q < 2; ++q) {
            bwr[0 * SBH + arow + 16 * q] = cvt_pk(pb[q].x, pb[q].y);
            bwr[1 * SBH + arow + 16 * q] = cvt_pk(pb[q].z, pb[q].w);
        }
        __syncthreads();

        // issue next tile's global loads (hide under compute)
        if (kt + 1 < NTILES) {
            const float* An = Ap + (kt + 1) * BK;
            const float* Wn = Wp + (kt + 1) * BK;
#pragma unroll
            for (int q = 0; q < 4; ++q)
                pa[q] = *(const float4*)(An + (size_t)(arow + 16 * q) * K_DIM);
#pragma unroll
            for (int q = 0; q < 2; ++q)
                pb[q] = *(const float4*)(Wn + (size_t)(arow + 16 * q) * K_DIM);
        }

        // compute: 32 k-pair rows, constant LDS offsets, pk-f16 math
#pragma unroll
        for (int kk2 = 0; kk2 < KP; ++kk2) {
            const h4 a01 = *(const h4*)(Ard + kk2 * SAH);      // m+0, m+1
            const h4 a23 = *(const h4*)(Ard + kk2 * SAH + 2);  // m+2, m+3
            const h4 b01 = *(const h4*)(Brd + kk2 * SBH);      // n+0, n+1
            const h2 am[4] = {a01.xy, a01.zw, a23.xy, a23.zw};
            const h2 bn[2] = {b01.xy, b01.zw};
#pragma unroll
            for (int i = 0; i < 4; ++i)
#pragma unroll
                for (int j = 0; j < 2; ++j) {
                    const h2 p = am[i] * bn[j];                             // v_pk_mul_f16
                    pmax[i][j] = __builtin_elementwise_max(pmax[i][j], p);  // v_pk_max_f16
                    pmin[i][j] = __builtin_elementwise_min(pmin[i][j], p);  // v_pk_min_f16
                }
        }
    }

    // epilogue: combine even/odd extrema, add bias, store f32
#pragma unroll
    for (int i = 0; i < 4; ++i) {
        float2 o;
        o.x = fmaxf((float)pmax[i][0].x, (float)pmax[i][0].y)
            + fminf((float)pmin[i][0].x, (float)pmin[i][0].y) + bb0;
        o.y = fmaxf((float)pmax[i][1].x, (float)pmax[i][1].y)
            + fminf((float)pmin[i][1].x, (float)pmin[i][1].y) + bb1;
        *(float2*)&out[(size_t)(m0 + mt * 4 + i) * N_DIM + n0 + nt * 2] = o;
    }
}

extern "C" void kernel_launch(void* const* d_in, const int* in_sizes, int n_in,
                              void* d_out, int out_size, void* d_ws, size_t ws_size,
                              hipStream_t stream) {
    const float* x    = (const float*)d_in[0];   // [2,1024,768] -> [2048,768]
    const float* w    = (const float*)d_in[1];   // [768,768] row-major [N][K]
    const float* bias = (const float*)d_in[2];   // [768]
    float* out = (float*)d_out;                  // [2048,768]

    dim3 grid(N_DIM / BN, M_DIM / BM);           // (24, 32) = 768 blocks = 3/CU
    mam_kernel<<<grid, 256, 0, stream>>>(x, w, bias, out);
}